// Round 20
// baseline (50.843 us; speedup 1.0000x reference)
//
#include <hip/hip_runtime.h>
#include <hip/hip_bf16.h>

// BinaryReflectanceGate: pointwise MLP (4->16->16, relu) -> segment max over
// sorted batch ids [B=64] -> 2-logit gate + gumbel softmax -> scale reflectance.
//
// Round-20 = r18's A-geometry x r19's scan-free B (each half proven alone):
//   r18 evidence: PTW=512 + __launch_bounds__(256,8) made kernel A faster
//     (profiled 60->42us, occ 28->48%, VALUBusy 17->27%) but its B re-scanned
//     a doubled pid array (64MB) and ate the gain.
//   r19 evidence: direct-atomicMax segmax + scan-free B is cost-neutral and
//     has NO per-NBLK B cost -> combining captures A's gain without B's loss.
//   memset: segmax[64][16]=0 (relu => 0 is max-identity).
//   A: SITERS=2, NBLK=2048, bounds(256,8); LDS weights; block combine ->
//      global atomicMax (64K staggered atomics) + recs[2048].
//   B: 2 threads read segmax rows (L2-hot), sigmoids, scale 1024 pts/block.
//
// MFMA layout facts (HW-verified r4, absmax 0.0039):
//   C/D: col=lane&15, row=(lane>>4)*4+reg. Lane l owns points 4l..4l+3 of each
//   256-pt chunk (pos floats 12l..12l+11 = 3 aligned float4s + refl float4).
//   In MFMA (j,t), lanes with g==t feed their j-th point; column c's point id
//   = sb + 4*(16t+c) + j (closed form, used for straddle select).

#define N_PTS 4194304
#define NB 64
#define NH 16
#define WPB 4                       // waves per block
#define SITERS 2                    // 256-pt chunks per wave
#define PTW (256 * SITERS)          // 512 points per wave
#define PPB (WPB * PTW)             // 2048 points per block
#define NBLK (N_PTS / PPB)          // 2048 blocks -> 8 waves/SIMD

typedef __attribute__((ext_vector_type(8))) short bf16x8;
typedef __attribute__((ext_vector_type(4))) float f32x4;
union U8 { bf16x8 v; unsigned u[4]; unsigned short s[8]; };

struct Rec { int idA, idB, bpos; };

__device__ __forceinline__ unsigned pk2(float a, float b) {
    float2 t; t.x = a; t.y = b;
    __hip_bfloat162 r = __float22bfloat162_rn(t);
    unsigned u;
    __builtin_memcpy(&u, &r, sizeof(u));
    return u;
}
__device__ __forceinline__ unsigned short f2bf(float x) {   // RNE, setup only
    unsigned u = __float_as_uint(x);
    u = u + 0x7fffu + ((u >> 16) & 1u);
    return (unsigned short)(u >> 16);
}

// One 256-pt chunk: lane's 4 points through both layers, phase-split for ILP.
template<bool SLOW>
__device__ __forceinline__ void do_chunk(
    const float4& q0, const float4& q1, const float4& q2, const float4& rr,
    int sb, int g, int col, int bposw,
    const U8& A1, const U8& A2, const f32x4& c1, const f32x4& c2,
    f32x4& accA, f32x4& accB)
{
    const float f[4][4] = {{q0.x, q0.y, q0.z, rr.x},
                           {q0.w, q1.x, q1.y, rr.y},
                           {q1.z, q1.w, q2.x, rr.z},
                           {q2.y, q2.z, q2.w, rr.w}};
#pragma unroll
    for (int j = 0; j < 4; ++j) {
        const unsigned F01 = pk2(f[j][0], f[j][1]);
        const unsigned F23 = pk2(f[j][2], f[j][3]);
        f32x4 d[4], h[4];                 // static-indexed (fully unrolled)
#pragma unroll
        for (int t = 0; t < 4; ++t) {     // phase 1: 4 independent MFMA1
            const bool mine = (g == t);
            U8 B;
            B.u[0] = mine ? F01 : 0u;
            B.u[1] = mine ? F23 : 0u;
            B.u[2] = 0u; B.u[3] = 0u;
            d[t] = __builtin_amdgcn_mfma_f32_16x16x32_bf16(A1.v, B.v, c1, 0, 0, 0);
        }
#pragma unroll
        for (int t = 0; t < 4; ++t) {     // phase 2+3: pack, 4 MFMA2
            U8 P;
            P.u[0] = pk2(fmaxf(d[t][0], 0.f), fmaxf(d[t][1], 0.f));
            P.u[1] = pk2(fmaxf(d[t][2], 0.f), fmaxf(d[t][3], 0.f));
            P.u[2] = 0u; P.u[3] = 0u;
            h[t] = __builtin_amdgcn_mfma_f32_16x16x32_bf16(A2.v, P.v, c2, 0, 0, 0);
        }
#pragma unroll
        for (int t = 0; t < 4; ++t) {     // phase 4: accumulate
            if (!SLOW) {
#pragma unroll
                for (int r = 0; r < 4; ++r) accA[r] = fmaxf(accA[r], h[t][r]);
            } else {
                const bool m = (sb + 4 * (16 * t + col) + j) < bposw;
#pragma unroll
                for (int r = 0; r < 4; ++r) {
                    accA[r] = fmaxf(accA[r], m ? h[t][r] : 0.f);
                    accB[r] = fmaxf(accB[r], m ? 0.f : h[t][r]);
                }
            }
        }
    }
}

// ---------------- A: MLP + segment-max -> global atomics + records ----------------
__global__ __launch_bounds__(256, 8) void mlp_segmax_kernel(
    const float* __restrict__ pos,    // [N,3]
    const float* __restrict__ refl,   // [N]
    const int*   __restrict__ batch,  // [N] sorted
    const float* __restrict__ W1, const float* __restrict__ b1,
    const float* __restrict__ W2, const float* __restrict__ b2,
    unsigned*    __restrict__ segmax, // [64,16] float bits, pre-zeroed
    Rec*         __restrict__ recs)   // [NBLK]
{
    __shared__ float wlds[352];       // W1[64] | b1[16] | W2[256] | b2[16]
    __shared__ float lv[WPB][2][NH];
    __shared__ int   li[WPB][2];
    __shared__ int   lbp[WPB];

    const int tid  = threadIdx.x;
    const int lane = tid & 63;
    const int wid  = tid >> 6;
    const int col  = lane & 15;
    const int g    = lane >> 4;
    const int wb   = (blockIdx.x * WPB + wid) * PTW;

    // ---- block-cooperative coalesced weight staging ----
    if (tid < 64)  wlds[tid]        = W1[tid];
    if (tid < 16)  wlds[64 + tid]   = b1[tid];
    wlds[80 + tid] = W2[tid];        // 256 threads, 256 floats
    if (tid < 16)  wlds[336 + tid]  = b2[tid];
    __syncthreads();

    U8 A1, A2;
#pragma unroll
    for (int e = 0; e < 4; ++e) {
        A1.s[e]     = f2bf(wlds[e * NH + col]);
        A1.s[e + 4] = 0;
        A2.s[e]     = f2bf(wlds[80 + (4 * g + e) * NH + col]);
        A2.s[e + 4] = 0;
    }
    f32x4 c1, c2;
#pragma unroll
    for (int r = 0; r < 4; ++r) {
        c1[r] = wlds[64 + 4 * g + r];
        c2[r] = wlds[336 + 4 * g + r];
    }

    const int idA = batch[wb];
    const int idB = batch[wb + PTW - 1];
    const bool isSlow = (idA != idB);      // wave-uniform

    f32x4 accA = {0.f, 0.f, 0.f, 0.f};
    f32x4 accB = {0.f, 0.f, 0.f, 0.f};

    const float4* gp = (const float4*)(pos + (size_t)wb * 3);
    const float4* gr = (const float4*)(refl + wb);

    float4 q0 = gp[3 * lane + 0];
    float4 q1 = gp[3 * lane + 1];
    float4 q2 = gp[3 * lane + 2];
    float4 rr = gr[lane];

    if (!isSlow) {
        // ---- fast path: straight-line, rolling prefetch ----
#pragma unroll
        for (int s = 0; s < SITERS; ++s) {
            float4 n0, n1, n2, nr;
            if (s + 1 < SITERS) {
                n0 = gp[(s + 1) * 192 + 3 * lane + 0];
                n1 = gp[(s + 1) * 192 + 3 * lane + 1];
                n2 = gp[(s + 1) * 192 + 3 * lane + 2];
                nr = gr[(s + 1) * 64 + lane];
            }
            do_chunk<false>(q0, q1, q2, rr, wb + s * 256, g, col, 0,
                            A1, A2, c1, c2, accA, accB);
            if (s + 1 < SITERS) { q0 = n0; q1 = n1; q2 = n2; rr = nr; }
        }
    } else {
        // ---- slow path (~127 waves): boundary scan, then select-accumulate
        int bposw = 0x7fffffff;
        for (int it = 0; it < PTW / 64; ++it) {
            const int idx = wb + it * 64 + lane;
            const unsigned long long mk = __ballot(batch[idx] != idA);
            if (mk) bposw = min(bposw, wb + it * 64 + (__ffsll((long long)mk) - 1));
        }
#pragma unroll
        for (int s = 0; s < SITERS; ++s) {
            float4 n0, n1, n2, nr;
            if (s + 1 < SITERS) {
                n0 = gp[(s + 1) * 192 + 3 * lane + 0];
                n1 = gp[(s + 1) * 192 + 3 * lane + 1];
                n2 = gp[(s + 1) * 192 + 3 * lane + 2];
                nr = gr[(s + 1) * 64 + lane];
            }
            do_chunk<true>(q0, q1, q2, rr, wb + s * 256, g, col, bposw,
                           A1, A2, c1, c2, accA, accB);
            if (s + 1 < SITERS) { q0 = n0; q1 = n1; q2 = n2; rr = nr; }
        }
        lbp[wid] = bposw;
    }

    // ---- wave reduce across the 16 columns ----
#pragma unroll
    for (int mk = 1; mk <= 8; mk <<= 1) {
#pragma unroll
        for (int r = 0; r < 4; ++r) {
            accA[r] = fmaxf(accA[r], __shfl_xor(accA[r], mk));
            accB[r] = fmaxf(accB[r], __shfl_xor(accB[r], mk));
        }
    }
    if (col == 0) {   // lanes 0,16,32,48 hold dims 4g..4g+3
        *reinterpret_cast<float4*>(&lv[wid][0][4 * g]) =
            make_float4(accA[0], accA[1], accA[2], accA[3]);
        *reinterpret_cast<float4*>(&lv[wid][1][4 * g]) =
            make_float4(accB[0], accB[1], accB[2], accB[3]);
    }
    if (lane == 0) {
        li[wid][0] = idA; li[wid][1] = idB;
        if (!isSlow) lbp[wid] = 0x7fffffff;
    }
    __syncthreads();

    // ---- block combine -> DIRECT global atomicMax (staggered) ----
    if (tid < NH) {
        const int d   = tid;
        const int ida = li[0][0];
        const int idb = li[WPB - 1][1];
        float mA = 0.f, mB = 0.f;
#pragma unroll
        for (int s = 0; s < WPB; ++s)
#pragma unroll
            for (int hh = 0; hh < 2; ++hh) {
                const float val = lv[s][hh][d];
                if (li[s][hh] == ida) mA = fmaxf(mA, val);
                else                  mB = fmaxf(mB, val);
            }
        atomicMax(segmax + ida * NH + d, __float_as_uint(mA));   // vals >= 0
        if (idb != ida)
            atomicMax(segmax + idb * NH + d, __float_as_uint(mB));
        if (d == 0) {
            int bp = 0x7fffffff;
#pragma unroll
            for (int s = 0; s < WPB; ++s) {
                if (li[s][0] != ida) bp = min(bp, (int)(blockIdx.x * PPB + s * PTW));
                else if (lbp[s] != 0x7fffffff) bp = min(bp, lbp[s]);
            }
            Rec r; r.idA = ida; r.idB = idb; r.bpos = bp;
            recs[blockIdx.x] = r;
        }
    }
}

// ---------------- B: gate from segmax rows + scale (scan-free, r19) ----------------
__global__ __launch_bounds__(256) void gate_scale_kernel(
    const float* __restrict__ refl,
    const unsigned* __restrict__ segmax, // [64,16] float bits
    const Rec*   __restrict__ recs,      // [NBLK]
    const float* __restrict__ Wg, const float* __restrict__ bg,
    const float* __restrict__ gum,
    float* __restrict__ out)
{
    __shared__ float gAB[2];

    const int tid = threadIdx.x;
    const Rec rec = recs[blockIdx.x >> 1];     // 2 scale-blocks per A-block

    // ---- 2 threads compute the 2 gates from L2-hot segmax rows ----
    if (tid < 2) {
        const int bsel = tid ? rec.idB : rec.idA;
        float l0 = bg[0] + gum[bsel * 2 + 0];
        float l1 = bg[1] + gum[bsel * 2 + 1];
#pragma unroll
        for (int k = 0; k < NH; ++k) {
            const float s = __uint_as_float(segmax[bsel * NH + k]);
            l0 = fmaf(s, Wg[k * 2 + 0], l0);
            l1 = fmaf(s, Wg[k * 2 + 1], l1);
        }
        gAB[tid] = 1.f / (1.f + expf(-(l1 - l0)));   // softmax[:,1], TAU=1
    }
    __syncthreads();

    const float gA = gAB[0];
    const float gB = (rec.idA == rec.idB) ? gAB[0] : gAB[1];

    // ---- scale own 1024 points ----
    const int p0 = (blockIdx.x * 256 + tid) * 4;
    const float4 rv = *reinterpret_cast<const float4*>(refl + p0);
    float4 o;
    o.x = ((p0 + 0) < rec.bpos ? gA : gB) * rv.x;
    o.y = ((p0 + 1) < rec.bpos ? gA : gB) * rv.y;
    o.z = ((p0 + 2) < rec.bpos ? gA : gB) * rv.z;
    o.w = ((p0 + 3) < rec.bpos ? gA : gB) * rv.w;
    *reinterpret_cast<float4*>(out + p0) = o;
}

extern "C" void kernel_launch(void* const* d_in, const int* in_sizes, int n_in,
                              void* d_out, int out_size, void* d_ws, size_t ws_size,
                              hipStream_t stream) {
    const float* pos   = (const float*)d_in[0];
    const float* refl  = (const float*)d_in[1];
    const int*   batch = (const int*)d_in[2];
    const float* gumb  = (const float*)d_in[3];
    const float* W1    = (const float*)d_in[4];
    const float* b1    = (const float*)d_in[5];
    const float* W2    = (const float*)d_in[6];
    const float* b2    = (const float*)d_in[7];
    const float* Wg    = (const float*)d_in[8];
    const float* bg    = (const float*)d_in[9];
    float* out = (float*)d_out;

    // ws layout: segmax 4KB | recs 24KB
    unsigned* segmax = (unsigned*)d_ws;
    Rec*      recs   = (Rec*)((char*)d_ws + 4096);

    (void)hipMemsetAsync(segmax, 0, NB * NH * sizeof(unsigned), stream);
    mlp_segmax_kernel<<<NBLK, 256, 0, stream>>>(pos, refl, batch,
                                                W1, b1, W2, b2, segmax, recs);
    gate_scale_kernel<<<N_PTS / 1024, 256, 0, stream>>>(refl, segmax, recs,
                                                        Wg, bg, gumb, out);
}

// Round 21
// 39.080 us; speedup vs baseline: 1.3010x; 1.3010x over previous
//
#include <hip/hip_runtime.h>
#include <hip/hip_bf16.h>

// BinaryReflectanceGate: pointwise MLP (4->16->16, relu) -> segment max over
// sorted batch ids [B=64] -> 2-logit gate + gumbel softmax -> scale reflectance.
//
// FINAL (= round-15, session best 38.88us):
//   A (mlp_segmax): MFMA MLP, 1024 blk x 4 waves x 1024 pts; LDS-staged
//     weights; straight-line phase-split do_chunk; per-block partials
//     pv/pid + recs{idA,idB,bpos} (block spans <=2 sorted segments).
//   B (gate_scale): per 1024-pt block: scan pid[2048] (8KB, L2-hot) ->
//     LDS list of matching entries -> LDS atomicMax segmax[2][16] ->
//     2 sigmoids -> scale. No single-block serialization anywhere.
//
// Session ledger (falsified theories for A's residual ~2x-over-floor):
//   atomic fan-in (r1->r3 fixed), LDS staging (r7 race, r8 barrier-bound),
//   TLP geometry (r11, r18, r20 all regress), load-depth/pipelining (r9,
//   r10, r12, r13-asm: VGPR tell-tale shows compiler folds all rings),
//   VMEM transactions (r16 coalesced map: flat), dep-chain serialization
//   (r17 fence: VGPR 40->64, flat), grid-sync fusion (r14: 222us),
//   atomic topology (r19 flat, r20 cross-XCD writeback storm).
//
// MFMA layout facts (HW-verified r4, absmax 0.0039):
//   C/D: col=lane&15, row=(lane>>4)*4+reg. Lane l owns points 4l..4l+3 of each
//   256-pt chunk (pos floats 12l..12l+11 = 3 aligned float4s + refl float4).
//   In MFMA (j,t), lanes with g==t feed their j-th point; column c's point id
//   = sb + 4*(16t+c) + j (closed form, used for straddle select).

#define N_PTS 4194304
#define NB 64
#define NH 16
#define WPB 4                       // waves per block
#define SITERS 4                    // 256-pt chunks per wave
#define PTW (256 * SITERS)          // 1024 points per wave
#define PPB (WPB * PTW)             // 4096 points per block
#define NBLK (N_PTS / PPB)          // 1024 blocks
#define NENT (NBLK * 2)             // 2048 partial entries

typedef __attribute__((ext_vector_type(8))) short bf16x8;
typedef __attribute__((ext_vector_type(4))) float f32x4;
union U8 { bf16x8 v; unsigned u[4]; unsigned short s[8]; };

struct Rec { int idA, idB, bpos; };

__device__ __forceinline__ unsigned pk2(float a, float b) {
    float2 t; t.x = a; t.y = b;
    __hip_bfloat162 r = __float22bfloat162_rn(t);
    unsigned u;
    __builtin_memcpy(&u, &r, sizeof(u));
    return u;
}
__device__ __forceinline__ unsigned short f2bf(float x) {   // RNE, setup only
    unsigned u = __float_as_uint(x);
    u = u + 0x7fffu + ((u >> 16) & 1u);
    return (unsigned short)(u >> 16);
}

// One 256-pt chunk: lane's 4 points through both layers, phase-split for ILP.
template<bool SLOW>
__device__ __forceinline__ void do_chunk(
    const float4& q0, const float4& q1, const float4& q2, const float4& rr,
    int sb, int g, int col, int bposw,
    const U8& A1, const U8& A2, const f32x4& c1, const f32x4& c2,
    f32x4& accA, f32x4& accB)
{
    const float f[4][4] = {{q0.x, q0.y, q0.z, rr.x},
                           {q0.w, q1.x, q1.y, rr.y},
                           {q1.z, q1.w, q2.x, rr.z},
                           {q2.y, q2.z, q2.w, rr.w}};
#pragma unroll
    for (int j = 0; j < 4; ++j) {
        const unsigned F01 = pk2(f[j][0], f[j][1]);
        const unsigned F23 = pk2(f[j][2], f[j][3]);
        f32x4 d[4], h[4];                 // static-indexed (fully unrolled)
#pragma unroll
        for (int t = 0; t < 4; ++t) {     // phase 1: 4 independent MFMA1
            const bool mine = (g == t);
            U8 B;
            B.u[0] = mine ? F01 : 0u;
            B.u[1] = mine ? F23 : 0u;
            B.u[2] = 0u; B.u[3] = 0u;
            d[t] = __builtin_amdgcn_mfma_f32_16x16x32_bf16(A1.v, B.v, c1, 0, 0, 0);
        }
#pragma unroll
        for (int t = 0; t < 4; ++t) {     // phase 2+3: pack, 4 MFMA2
            U8 P;
            P.u[0] = pk2(fmaxf(d[t][0], 0.f), fmaxf(d[t][1], 0.f));
            P.u[1] = pk2(fmaxf(d[t][2], 0.f), fmaxf(d[t][3], 0.f));
            P.u[2] = 0u; P.u[3] = 0u;
            h[t] = __builtin_amdgcn_mfma_f32_16x16x32_bf16(A2.v, P.v, c2, 0, 0, 0);
        }
#pragma unroll
        for (int t = 0; t < 4; ++t) {     // phase 4: accumulate
            if (!SLOW) {
#pragma unroll
                for (int r = 0; r < 4; ++r) accA[r] = fmaxf(accA[r], h[t][r]);
            } else {
                const bool m = (sb + 4 * (16 * t + col) + j) < bposw;
#pragma unroll
                for (int r = 0; r < 4; ++r) {
                    accA[r] = fmaxf(accA[r], m ? h[t][r] : 0.f);
                    accB[r] = fmaxf(accB[r], m ? 0.f : h[t][r]);
                }
            }
        }
    }
}

// ---------------- A: MLP + segment-max partials + records ----------------
__global__ __launch_bounds__(256, 4) void mlp_segmax_kernel(
    const float* __restrict__ pos,    // [N,3]
    const float* __restrict__ refl,   // [N]
    const int*   __restrict__ batch,  // [N] sorted
    const float* __restrict__ W1, const float* __restrict__ b1,
    const float* __restrict__ W2, const float* __restrict__ b2,
    float* __restrict__ pv,           // [NENT,16]
    int*   __restrict__ pid,          // [NENT]
    Rec*   __restrict__ recs)         // [NBLK]
{
    __shared__ float wlds[352];       // W1[64] | b1[16] | W2[256] | b2[16]
    __shared__ float lv[WPB][2][NH];
    __shared__ int   li[WPB][2];
    __shared__ int   lbp[WPB];

    const int tid  = threadIdx.x;
    const int lane = tid & 63;
    const int wid  = tid >> 6;
    const int col  = lane & 15;
    const int g    = lane >> 4;
    const int wb   = (blockIdx.x * WPB + wid) * PTW;

    // ---- block-cooperative coalesced weight staging ----
    if (tid < 64)  wlds[tid]        = W1[tid];
    if (tid < 16)  wlds[64 + tid]   = b1[tid];
    wlds[80 + tid] = W2[tid];        // 256 threads, 256 floats
    if (tid < 16)  wlds[336 + tid]  = b2[tid];
    __syncthreads();

    U8 A1, A2;
#pragma unroll
    for (int e = 0; e < 4; ++e) {
        A1.s[e]     = f2bf(wlds[e * NH + col]);
        A1.s[e + 4] = 0;
        A2.s[e]     = f2bf(wlds[80 + (4 * g + e) * NH + col]);
        A2.s[e + 4] = 0;
    }
    f32x4 c1, c2;
#pragma unroll
    for (int r = 0; r < 4; ++r) {
        c1[r] = wlds[64 + 4 * g + r];
        c2[r] = wlds[336 + 4 * g + r];
    }

    const int idA = batch[wb];
    const int idB = batch[wb + PTW - 1];
    const bool isSlow = (idA != idB);      // wave-uniform

    f32x4 accA = {0.f, 0.f, 0.f, 0.f};
    f32x4 accB = {0.f, 0.f, 0.f, 0.f};

    const float4* gp = (const float4*)(pos + (size_t)wb * 3);
    const float4* gr = (const float4*)(refl + wb);

    float4 q0 = gp[3 * lane + 0];
    float4 q1 = gp[3 * lane + 1];
    float4 q2 = gp[3 * lane + 2];
    float4 rr = gr[lane];

    if (!isSlow) {
        // ---- fast path: straight-line, rolling prefetch ----
#pragma unroll
        for (int s = 0; s < SITERS; ++s) {
            float4 n0, n1, n2, nr;
            if (s + 1 < SITERS) {
                n0 = gp[(s + 1) * 192 + 3 * lane + 0];
                n1 = gp[(s + 1) * 192 + 3 * lane + 1];
                n2 = gp[(s + 1) * 192 + 3 * lane + 2];
                nr = gr[(s + 1) * 64 + lane];
            }
            do_chunk<false>(q0, q1, q2, rr, wb + s * 256, g, col, 0,
                            A1, A2, c1, c2, accA, accB);
            if (s + 1 < SITERS) { q0 = n0; q1 = n1; q2 = n2; rr = nr; }
        }
    } else {
        // ---- slow path (~63 waves): boundary scan, then select-accumulate
        int bposw = 0x7fffffff;
        for (int it = 0; it < PTW / 64; ++it) {
            const int idx = wb + it * 64 + lane;
            const unsigned long long mk = __ballot(batch[idx] != idA);
            if (mk) bposw = min(bposw, wb + it * 64 + (__ffsll((long long)mk) - 1));
        }
#pragma unroll
        for (int s = 0; s < SITERS; ++s) {
            float4 n0, n1, n2, nr;
            if (s + 1 < SITERS) {
                n0 = gp[(s + 1) * 192 + 3 * lane + 0];
                n1 = gp[(s + 1) * 192 + 3 * lane + 1];
                n2 = gp[(s + 1) * 192 + 3 * lane + 2];
                nr = gr[(s + 1) * 64 + lane];
            }
            do_chunk<true>(q0, q1, q2, rr, wb + s * 256, g, col, bposw,
                           A1, A2, c1, c2, accA, accB);
            if (s + 1 < SITERS) { q0 = n0; q1 = n1; q2 = n2; rr = nr; }
        }
        lbp[wid] = bposw;
    }

    // ---- wave reduce across the 16 columns ----
#pragma unroll
    for (int mk = 1; mk <= 8; mk <<= 1) {
#pragma unroll
        for (int r = 0; r < 4; ++r) {
            accA[r] = fmaxf(accA[r], __shfl_xor(accA[r], mk));
            accB[r] = fmaxf(accB[r], __shfl_xor(accB[r], mk));
        }
    }
    if (col == 0) {   // lanes 0,16,32,48 hold dims 4g..4g+3
        *reinterpret_cast<float4*>(&lv[wid][0][4 * g]) =
            make_float4(accA[0], accA[1], accA[2], accA[3]);
        *reinterpret_cast<float4*>(&lv[wid][1][4 * g]) =
            make_float4(accB[0], accB[1], accB[2], accB[3]);
    }
    if (lane == 0) {
        li[wid][0] = idA; li[wid][1] = idB;
        if (!isSlow) lbp[wid] = 0x7fffffff;
    }
    __syncthreads();

    // ---- block combine (<=2 segments per 4096-pt block) ----
    if (tid < NH) {
        const int d   = tid;
        const int ida = li[0][0];
        const int idb = li[WPB - 1][1];
        float mA = 0.f, mB = 0.f;
#pragma unroll
        for (int s = 0; s < WPB; ++s)
#pragma unroll
            for (int hh = 0; hh < 2; ++hh) {
                const float val = lv[s][hh][d];
                if (li[s][hh] == ida) mA = fmaxf(mA, val);
                else                  mB = fmaxf(mB, val);
            }
        pv[(blockIdx.x * 2 + 0) * NH + d] = mA;
        pv[(blockIdx.x * 2 + 1) * NH + d] = mB;
        if (d == 0) {
            pid[blockIdx.x * 2 + 0] = ida;
            pid[blockIdx.x * 2 + 1] = idb;
            int bp = 0x7fffffff;
#pragma unroll
            for (int s = 0; s < WPB; ++s) {
                if (li[s][0] != ida) bp = min(bp, (int)(blockIdx.x * PPB + s * PTW));
                else if (lbp[s] != 0x7fffffff) bp = min(bp, lbp[s]);
            }
            Rec r; r.idA = ida; r.idB = idb; r.bpos = bp;
            recs[blockIdx.x] = r;
        }
    }
}

// ---------------- B: fused gate + scale ----------------
__global__ __launch_bounds__(256) void gate_scale_kernel(
    const float* __restrict__ refl,
    const float* __restrict__ pv,     // [NENT,16]
    const int*   __restrict__ pid,    // [NENT]
    const Rec*   __restrict__ recs,   // [NBLK]
    const float* __restrict__ Wg, const float* __restrict__ bg,
    const float* __restrict__ gum,
    float* __restrict__ out)
{
    __shared__ unsigned smA[NH], smB[NH];
    __shared__ unsigned short list[128];
    __shared__ unsigned cnt;
    __shared__ float gAB[2];

    const int tid = threadIdx.x;
    const Rec rec = recs[blockIdx.x >> 2];     // 4 scale-blocks per A-block

    if (tid < NH) { smA[tid] = 0u; smB[tid] = 0u; }
    if (tid == 0) cnt = 0u;
    __syncthreads();

    // ---- scan pid (8KB, coalesced, L2-hot): collect matching entries ----
#pragma unroll
    for (int k = 0; k < NENT / 256; ++k) {
        const int e = k * 256 + tid;
        const int p = pid[e];
        const bool a = (p == rec.idA);
        const bool b = (p == rec.idB) && !a;
        if (a || b) {
            const unsigned i = atomicAdd(&cnt, 1u);
            if (i < 128u) list[i] = (unsigned short)(e | (a ? 0 : 0x8000));
        }
    }
    __syncthreads();

    // ---- gather + LDS max-reduce only the matching pv rows (~70) ----
    const int n = (int)(cnt < 128u ? cnt : 128u);
    for (int k = tid; k < n * NH; k += 256) {
        const int i = k >> 4, d = k & 15;
        const int e = list[i] & 0x7fff;
        unsigned* dst = (list[i] & 0x8000) ? smB : smA;
        atomicMax(dst + d, __float_as_uint(pv[e * NH + d]));
    }
    __syncthreads();

    // ---- 2 threads compute the 2 gates ----
    if (tid < 2) {
        const int bsel = tid ? rec.idB : rec.idA;
        const unsigned* sm = tid ? smB : smA;
        float l0 = bg[0] + gum[bsel * 2 + 0];
        float l1 = bg[1] + gum[bsel * 2 + 1];
#pragma unroll
        for (int k = 0; k < NH; ++k) {
            const float s = __uint_as_float(sm[k]);
            l0 = fmaf(s, Wg[k * 2 + 0], l0);
            l1 = fmaf(s, Wg[k * 2 + 1], l1);
        }
        gAB[tid] = 1.f / (1.f + expf(-(l1 - l0)));   // softmax[:,1], TAU=1
    }
    __syncthreads();

    const float gA = gAB[0];
    const float gB = (rec.idA == rec.idB) ? gAB[0] : gAB[1];

    // ---- scale own 1024 points ----
    const int p0 = (blockIdx.x * 256 + tid) * 4;
    const float4 rv = *reinterpret_cast<const float4*>(refl + p0);
    float4 o;
    o.x = ((p0 + 0) < rec.bpos ? gA : gB) * rv.x;
    o.y = ((p0 + 1) < rec.bpos ? gA : gB) * rv.y;
    o.z = ((p0 + 2) < rec.bpos ? gA : gB) * rv.z;
    o.w = ((p0 + 3) < rec.bpos ? gA : gB) * rv.w;
    *reinterpret_cast<float4*>(out + p0) = o;
}

extern "C" void kernel_launch(void* const* d_in, const int* in_sizes, int n_in,
                              void* d_out, int out_size, void* d_ws, size_t ws_size,
                              hipStream_t stream) {
    const float* pos   = (const float*)d_in[0];
    const float* refl  = (const float*)d_in[1];
    const int*   batch = (const int*)d_in[2];
    const float* gumb  = (const float*)d_in[3];
    const float* W1    = (const float*)d_in[4];
    const float* b1    = (const float*)d_in[5];
    const float* W2    = (const float*)d_in[6];
    const float* b2    = (const float*)d_in[7];
    const float* Wg    = (const float*)d_in[8];
    const float* bg    = (const float*)d_in[9];
    float* out = (float*)d_out;

    // ws layout: pv 128KB | pid 8KB | recs 12KB
    float* pv   = (float*)d_ws;
    int*   pid  = (int*)((char*)d_ws + 131072);
    Rec*   recs = (Rec*)((char*)d_ws + 139264);

    mlp_segmax_kernel<<<NBLK, 256, 0, stream>>>(pos, refl, batch,
                                                W1, b1, W2, b2, pv, pid, recs);
    gate_scale_kernel<<<N_PTS / 1024, 256, 0, stream>>>(refl, pv, pid, recs,
                                                        Wg, bg, gumb, out);
}

// Round 22
// 37.859 us; speedup vs baseline: 1.3430x; 1.0322x over previous
//
#include <hip/hip_runtime.h>
#include <hip/hip_bf16.h>

// BinaryReflectanceGate: pointwise MLP (4->16->16, relu) -> segment max over
// sorted batch ids [B=64] -> 2-logit gate + gumbel softmax -> scale reflectance.
//
// Round-22 = r18's A (validated: occ 48%, VALUBusy 27%, profiled 42us vs 58)
//          + B at HALF the blocks so pid-scan traffic returns to r15's 32MB.
//   A: SITERS=2, NBLK=2048, __launch_bounds__(256,8); coalesced point->lane
//      map (lane l owns {sb+l, sb+64+l, sb+128+l, sb+192+l}); LDS weights;
//      writes pv/pid/recs (NO global atomics -- r20's cross-XCD storm).
//   B: 2048 blocks x 2048 pts: scan pid[4096] (16KB, L2-hot) -> LDS list ->
//      LDS atomicMax segmax[2][16] -> 2 sigmoids -> scale 2 float4/thread.
//
// MFMA layout facts (HW-verified r4, absmax 0.0039):
//   C/D: col=lane&15, row=(lane>>4)*4+reg. In MFMA (j,t), lanes with g==t
//   feed their j-th point; column c of tile (j,t) holds point sb+64j+16t+c.

#define N_PTS 4194304
#define NB 64
#define NH 16
#define WPB 4                       // waves per block
#define SITERS 2                    // 256-pt chunks per wave
#define PTW (256 * SITERS)          // 512 points per wave
#define PPB (WPB * PTW)             // 2048 points per block
#define NBLK (N_PTS / PPB)          // 2048 blocks -> 8 waves/SIMD
#define NENT (NBLK * 2)             // 4096 partial entries

typedef __attribute__((ext_vector_type(8))) short bf16x8;
typedef __attribute__((ext_vector_type(4))) float f32x4;
union U8 { bf16x8 v; unsigned u[4]; unsigned short s[8]; };

struct Rec { int idA, idB, bpos; };
struct F3  { float x, y, z; };      // 12B packed point

__device__ __forceinline__ unsigned pk2(float a, float b) {
    float2 t; t.x = a; t.y = b;
    __hip_bfloat162 r = __float22bfloat162_rn(t);
    unsigned u;
    __builtin_memcpy(&u, &r, sizeof(u));
    return u;
}
__device__ __forceinline__ unsigned short f2bf(float x) {   // RNE, setup only
    unsigned u = __float_as_uint(x);
    u = u + 0x7fffu + ((u >> 16) & 1u);
    return (unsigned short)(u >> 16);
}

// One 256-pt chunk: lane's 4 points (stride-64 map) through both layers.
template<bool SLOW>
__device__ __forceinline__ void do_chunk(
    const F3 p[4], const float4& rv,
    int sb, int g, int col, int bposw,
    const U8& A1, const U8& A2, const f32x4& c1, const f32x4& c2,
    f32x4& accA, f32x4& accB)
{
    const float f[4][4] = {{p[0].x, p[0].y, p[0].z, rv.x},
                           {p[1].x, p[1].y, p[1].z, rv.y},
                           {p[2].x, p[2].y, p[2].z, rv.z},
                           {p[3].x, p[3].y, p[3].z, rv.w}};
#pragma unroll
    for (int j = 0; j < 4; ++j) {
        const unsigned F01 = pk2(f[j][0], f[j][1]);
        const unsigned F23 = pk2(f[j][2], f[j][3]);
        f32x4 d[4], h[4];                 // static-indexed (fully unrolled)
#pragma unroll
        for (int t = 0; t < 4; ++t) {     // phase 1: 4 independent MFMA1
            const bool mine = (g == t);
            U8 B;
            B.u[0] = mine ? F01 : 0u;
            B.u[1] = mine ? F23 : 0u;
            B.u[2] = 0u; B.u[3] = 0u;
            d[t] = __builtin_amdgcn_mfma_f32_16x16x32_bf16(A1.v, B.v, c1, 0, 0, 0);
        }
#pragma unroll
        for (int t = 0; t < 4; ++t) {     // phase 2+3: pack, 4 MFMA2
            U8 P;
            P.u[0] = pk2(fmaxf(d[t][0], 0.f), fmaxf(d[t][1], 0.f));
            P.u[1] = pk2(fmaxf(d[t][2], 0.f), fmaxf(d[t][3], 0.f));
            P.u[2] = 0u; P.u[3] = 0u;
            h[t] = __builtin_amdgcn_mfma_f32_16x16x32_bf16(A2.v, P.v, c2, 0, 0, 0);
        }
#pragma unroll
        for (int t = 0; t < 4; ++t) {     // phase 4: accumulate
            if (!SLOW) {
#pragma unroll
                for (int r = 0; r < 4; ++r) accA[r] = fmaxf(accA[r], h[t][r]);
            } else {
                // column c of tile (j,t) holds point sb + 64j + 16t + c
                const bool m = (sb + 64 * j + 16 * t + col) < bposw;
#pragma unroll
                for (int r = 0; r < 4; ++r) {
                    accA[r] = fmaxf(accA[r], m ? h[t][r] : 0.f);
                    accB[r] = fmaxf(accB[r], m ? 0.f : h[t][r]);
                }
            }
        }
    }
}

// ---------------- A: MLP + segment-max partials + records ----------------
__global__ __launch_bounds__(256, 8) void mlp_segmax_kernel(
    const float* __restrict__ pos,    // [N,3]
    const float* __restrict__ refl,   // [N]
    const int*   __restrict__ batch,  // [N] sorted
    const float* __restrict__ W1, const float* __restrict__ b1,
    const float* __restrict__ W2, const float* __restrict__ b2,
    float* __restrict__ pv,           // [NENT,16]
    int*   __restrict__ pid,          // [NENT]
    Rec*   __restrict__ recs)         // [NBLK]
{
    __shared__ float wlds[352];       // W1[64] | b1[16] | W2[256] | b2[16]
    __shared__ float lv[WPB][2][NH];
    __shared__ int   li[WPB][2];
    __shared__ int   lbp[WPB];

    const int tid  = threadIdx.x;
    const int lane = tid & 63;
    const int wid  = tid >> 6;
    const int col  = lane & 15;
    const int g    = lane >> 4;
    const int wb   = (blockIdx.x * WPB + wid) * PTW;

    // ---- block-cooperative coalesced weight staging ----
    if (tid < 64)  wlds[tid]        = W1[tid];
    if (tid < 16)  wlds[64 + tid]   = b1[tid];
    wlds[80 + tid] = W2[tid];        // 256 threads, 256 floats
    if (tid < 16)  wlds[336 + tid]  = b2[tid];
    __syncthreads();

    U8 A1, A2;
#pragma unroll
    for (int e = 0; e < 4; ++e) {
        A1.s[e]     = f2bf(wlds[e * NH + col]);
        A1.s[e + 4] = 0;
        A2.s[e]     = f2bf(wlds[80 + (4 * g + e) * NH + col]);
        A2.s[e + 4] = 0;
    }
    f32x4 c1, c2;
#pragma unroll
    for (int r = 0; r < 4; ++r) {
        c1[r] = wlds[64 + 4 * g + r];
        c2[r] = wlds[336 + 4 * g + r];
    }

    const int idA = batch[wb];
    const int idB = batch[wb + PTW - 1];
    const bool isSlow = (idA != idB);      // wave-uniform

    f32x4 accA = {0.f, 0.f, 0.f, 0.f};
    f32x4 accB = {0.f, 0.f, 0.f, 0.f};

    if (!isSlow) {
        // ---- fast path: coalesced dwordx3/dword loads, straight-line ----
#pragma unroll
        for (int s = 0; s < SITERS; ++s) {
            const int sb = wb + s * 256;
            const float* pb = pos + (size_t)sb * 3;
            const float* rb = refl + sb;
            F3 p[4];
            __builtin_memcpy(&p[0], pb + 3 * (0 * 64 + lane), 12);
            __builtin_memcpy(&p[1], pb + 3 * (1 * 64 + lane), 12);
            __builtin_memcpy(&p[2], pb + 3 * (2 * 64 + lane), 12);
            __builtin_memcpy(&p[3], pb + 3 * (3 * 64 + lane), 12);
            float4 rv;
            rv.x = rb[0 * 64 + lane];
            rv.y = rb[1 * 64 + lane];
            rv.z = rb[2 * 64 + lane];
            rv.w = rb[3 * 64 + lane];
            do_chunk<false>(p, rv, sb, g, col, 0,
                            A1, A2, c1, c2, accA, accB);
        }
    } else {
        // ---- slow path (~127 waves): boundary scan, then select-accumulate
        int bposw = 0x7fffffff;
        for (int it = 0; it < PTW / 64; ++it) {
            const int idx = wb + it * 64 + lane;
            const unsigned long long mk = __ballot(batch[idx] != idA);
            if (mk) bposw = min(bposw, wb + it * 64 + (__ffsll((long long)mk) - 1));
        }
#pragma unroll
        for (int s = 0; s < SITERS; ++s) {
            const int sb = wb + s * 256;
            const float* pb = pos + (size_t)sb * 3;
            const float* rb = refl + sb;
            F3 p[4];
            __builtin_memcpy(&p[0], pb + 3 * (0 * 64 + lane), 12);
            __builtin_memcpy(&p[1], pb + 3 * (1 * 64 + lane), 12);
            __builtin_memcpy(&p[2], pb + 3 * (2 * 64 + lane), 12);
            __builtin_memcpy(&p[3], pb + 3 * (3 * 64 + lane), 12);
            float4 rv;
            rv.x = rb[0 * 64 + lane];
            rv.y = rb[1 * 64 + lane];
            rv.z = rb[2 * 64 + lane];
            rv.w = rb[3 * 64 + lane];
            do_chunk<true>(p, rv, sb, g, col, bposw,
                           A1, A2, c1, c2, accA, accB);
        }
        lbp[wid] = bposw;
    }

    // ---- wave reduce across the 16 columns ----
#pragma unroll
    for (int mk = 1; mk <= 8; mk <<= 1) {
#pragma unroll
        for (int r = 0; r < 4; ++r) {
            accA[r] = fmaxf(accA[r], __shfl_xor(accA[r], mk));
            accB[r] = fmaxf(accB[r], __shfl_xor(accB[r], mk));
        }
    }
    if (col == 0) {   // lanes 0,16,32,48 hold dims 4g..4g+3
        *reinterpret_cast<float4*>(&lv[wid][0][4 * g]) =
            make_float4(accA[0], accA[1], accA[2], accA[3]);
        *reinterpret_cast<float4*>(&lv[wid][1][4 * g]) =
            make_float4(accB[0], accB[1], accB[2], accB[3]);
    }
    if (lane == 0) {
        li[wid][0] = idA; li[wid][1] = idB;
        if (!isSlow) lbp[wid] = 0x7fffffff;
    }
    __syncthreads();

    // ---- block combine (<=2 segments per 2048-pt block) ----
    if (tid < NH) {
        const int d   = tid;
        const int ida = li[0][0];
        const int idb = li[WPB - 1][1];
        float mA = 0.f, mB = 0.f;
#pragma unroll
        for (int s = 0; s < WPB; ++s)
#pragma unroll
            for (int hh = 0; hh < 2; ++hh) {
                const float val = lv[s][hh][d];
                if (li[s][hh] == ida) mA = fmaxf(mA, val);
                else                  mB = fmaxf(mB, val);
            }
        pv[(blockIdx.x * 2 + 0) * NH + d] = mA;
        pv[(blockIdx.x * 2 + 1) * NH + d] = mB;
        if (d == 0) {
            pid[blockIdx.x * 2 + 0] = ida;
            pid[blockIdx.x * 2 + 1] = idb;
            int bp = 0x7fffffff;
#pragma unroll
            for (int s = 0; s < WPB; ++s) {
                if (li[s][0] != ida) bp = min(bp, (int)(blockIdx.x * PPB + s * PTW));
                else if (lbp[s] != 0x7fffffff) bp = min(bp, lbp[s]);
            }
            Rec r; r.idA = ida; r.idB = idb; r.bpos = bp;
            recs[blockIdx.x] = r;
        }
    }
}

// ---------------- B: fused gate + scale (2048 pts/block) ----------------
__global__ __launch_bounds__(256) void gate_scale_kernel(
    const float* __restrict__ refl,
    const float* __restrict__ pv,     // [NENT,16]
    const int*   __restrict__ pid,    // [NENT]
    const Rec*   __restrict__ recs,   // [NBLK]
    const float* __restrict__ Wg, const float* __restrict__ bg,
    const float* __restrict__ gum,
    float* __restrict__ out)
{
    __shared__ unsigned smA[NH], smB[NH];
    __shared__ unsigned short list[256];
    __shared__ unsigned cnt;
    __shared__ float gAB[2];

    const int tid = threadIdx.x;
    const Rec rec = recs[blockIdx.x];          // 1 rec per 2048-pt block

    if (tid < NH) { smA[tid] = 0u; smB[tid] = 0u; }
    if (tid == 0) cnt = 0u;
    __syncthreads();

    // ---- scan pid (16KB, coalesced, L2-hot): collect matching entries ----
#pragma unroll
    for (int k = 0; k < NENT / 256; ++k) {
        const int e = k * 256 + tid;
        const int p = pid[e];
        const bool a = (p == rec.idA);
        const bool b = (p == rec.idB) && !a;
        if (a || b) {
            const unsigned i = atomicAdd(&cnt, 1u);
            if (i < 256u) list[i] = (unsigned short)(e | (a ? 0 : 0x8000));
        }
    }
    __syncthreads();

    // ---- gather + LDS max-reduce only the matching pv rows (~132) ----
    const int n = (int)(cnt < 256u ? cnt : 256u);
    for (int k = tid; k < n * NH; k += 256) {
        const int i = k >> 4, d = k & 15;
        const int e = list[i] & 0x7fff;
        unsigned* dst = (list[i] & 0x8000) ? smB : smA;
        atomicMax(dst + d, __float_as_uint(pv[e * NH + d]));
    }
    __syncthreads();

    // ---- 2 threads compute the 2 gates ----
    if (tid < 2) {
        const int bsel = tid ? rec.idB : rec.idA;
        const unsigned* sm = tid ? smB : smA;
        float l0 = bg[0] + gum[bsel * 2 + 0];
        float l1 = bg[1] + gum[bsel * 2 + 1];
#pragma unroll
        for (int k = 0; k < NH; ++k) {
            const float s = __uint_as_float(sm[k]);
            l0 = fmaf(s, Wg[k * 2 + 0], l0);
            l1 = fmaf(s, Wg[k * 2 + 1], l1);
        }
        gAB[tid] = 1.f / (1.f + expf(-(l1 - l0)));   // softmax[:,1], TAU=1
    }
    __syncthreads();

    const float gA = gAB[0];
    const float gB = (rec.idA == rec.idB) ? gAB[0] : gAB[1];

    // ---- scale own 2048 points (2 float4 per thread) ----
#pragma unroll
    for (int k = 0; k < 2; ++k) {
        const int p0 = blockIdx.x * PPB + (k * 256 + tid) * 4;
        const float4 rv = *reinterpret_cast<const float4*>(refl + p0);
        float4 o;
        o.x = ((p0 + 0) < rec.bpos ? gA : gB) * rv.x;
        o.y = ((p0 + 1) < rec.bpos ? gA : gB) * rv.y;
        o.z = ((p0 + 2) < rec.bpos ? gA : gB) * rv.z;
        o.w = ((p0 + 3) < rec.bpos ? gA : gB) * rv.w;
        *reinterpret_cast<float4*>(out + p0) = o;
    }
}

extern "C" void kernel_launch(void* const* d_in, const int* in_sizes, int n_in,
                              void* d_out, int out_size, void* d_ws, size_t ws_size,
                              hipStream_t stream) {
    const float* pos   = (const float*)d_in[0];
    const float* refl  = (const float*)d_in[1];
    const int*   batch = (const int*)d_in[2];
    const float* gumb  = (const float*)d_in[3];
    const float* W1    = (const float*)d_in[4];
    const float* b1    = (const float*)d_in[5];
    const float* W2    = (const float*)d_in[6];
    const float* b2    = (const float*)d_in[7];
    const float* Wg    = (const float*)d_in[8];
    const float* bg    = (const float*)d_in[9];
    float* out = (float*)d_out;

    // ws layout: pv 256KB | pid 16KB | recs 24KB
    float* pv   = (float*)d_ws;
    int*   pid  = (int*)((char*)d_ws + 262144);
    Rec*   recs = (Rec*)((char*)d_ws + 278528);

    mlp_segmax_kernel<<<NBLK, 256, 0, stream>>>(pos, refl, batch,
                                                W1, b1, W2, b2, pv, pid, recs);
    gate_scale_kernel<<<NBLK, 256, 0, stream>>>(refl, pv, pid, recs,
                                                Wg, bg, gumb, out);
}